// Round 8
// baseline (269.419 us; speedup 1.0000x reference)
//
#include <hip/hip_runtime.h>

#define TPB 256
#define BK_SHIFT 7
#define BK_SIZE 128
#define NBK_MAX 800     // >= ceil(100000/128)=782
#define EPT 32          // edges per thread in bin_scatter chunks

__device__ __forceinline__ unsigned short f2bf(float f) {
    unsigned u = __float_as_uint(f);
    unsigned r = (u + 0x7FFFu + ((u >> 16) & 1u)) >> 16;   // RNE
    return (unsigned short)r;
}
__device__ __forceinline__ float bf2f(unsigned short b) {
    return __uint_as_float((unsigned)b << 16);
}

// ---------------- bucket histogram (LDS-privatized, int4 loads) -----------
__global__ __launch_bounds__(256) void hist_buckets(
    const int* __restrict__ dst, int* __restrict__ bcnt, int E, int NBK)
{
    __shared__ int h[NBK_MAX];
    const int t = threadIdx.x;
    for (int i = t; i < NBK; i += 256) h[i] = 0;
    __syncthreads();
    const int E4 = E >> 2;
    for (int e4 = blockIdx.x * blockDim.x + t; e4 < E4; e4 += gridDim.x * blockDim.x) {
        int4 d = ((const int4*)dst)[e4];
        atomicAdd(&h[d.x >> BK_SHIFT], 1);
        atomicAdd(&h[d.y >> BK_SHIFT], 1);
        atomicAdd(&h[d.z >> BK_SHIFT], 1);
        atomicAdd(&h[d.w >> BK_SHIFT], 1);
    }
    if (blockIdx.x == 0) {
        for (int e = E4 * 4 + t; e < E; e += 256)
            atomicAdd(&h[dst[e] >> BK_SHIFT], 1);
    }
    __syncthreads();
    for (int i = t; i < NBK; i += 256)
        if (h[i]) atomicAdd(&bcnt[i], h[i]);
}

// ---------------- scan of bucket counts (one block, NBK<=1024) ------------
__global__ __launch_bounds__(1024) void scan_buckets(
    const int* __restrict__ bcnt, int* __restrict__ bbase,
    int* __restrict__ gcursor, int NBK)
{
    __shared__ int s[1024];
    const int t = threadIdx.x;
    int v = (t < NBK) ? bcnt[t] : 0;
    s[t] = v;
    __syncthreads();
    for (int off = 1; off < 1024; off <<= 1) {
        int u = (t >= off) ? s[t - off] : 0;
        __syncthreads();
        s[t] += u;
        __syncthreads();
    }
    if (t < NBK) {
        int excl = s[t] - v;
        bbase[t]   = excl;
        gcursor[t] = excl;
    }
}

// ---------------- bin scatter: pack edges into bucket-ordered pk[] --------
__global__ __launch_bounds__(256) void bin_scatter(
    const int* __restrict__ src, const int* __restrict__ dst,
    int* __restrict__ gcursor, int* __restrict__ pk, int E, int NBK)
{
    __shared__ int lcnt[NBK_MAX];
    __shared__ int lbase[NBK_MAX];
    __shared__ int lrank[NBK_MAX];
    const int t = threadIdx.x;
    const int e0 = blockIdx.x * (256 * EPT);

    for (int i = t; i < NBK; i += 256) { lcnt[i] = 0; lrank[i] = 0; }
    __syncthreads();

    #pragma unroll 4
    for (int k = 0; k < EPT; ++k) {
        int e = e0 + k * 256 + t;
        if (e < E) atomicAdd(&lcnt[dst[e] >> BK_SHIFT], 1);
    }
    __syncthreads();

    for (int i = t; i < NBK; i += 256) {
        int c = lcnt[i];
        if (c) lbase[i] = atomicAdd(&gcursor[i], c);
    }
    __syncthreads();

    #pragma unroll 4
    for (int k = 0; k < EPT; ++k) {
        int e = e0 + k * 256 + t;
        if (e < E) {
            int d = dst[e], s = src[e];
            int b = d >> BK_SHIFT;
            int r = atomicAdd(&lrank[b], 1);
            pk[lbase[b] + r] = (s << BK_SHIFT) | (d & (BK_SIZE - 1));
        }
    }
}

// ---------------- per-bucket counting sort -> exact CSR -------------------
__global__ __launch_bounds__(256) void bucket_csr(
    const int* __restrict__ pk, const int* __restrict__ bbase,
    const int* __restrict__ bcnt,
    int* __restrict__ csr_src, int* __restrict__ row_start,
    int* __restrict__ row_end, int N)
{
    __shared__ int lcnt[BK_SIZE];
    __shared__ int s[BK_SIZE];
    __shared__ int wcur[BK_SIZE];
    const int t = threadIdx.x;
    const int b = blockIdx.x;
    const int base = bbase[b];
    const int cnt  = bcnt[b];
    const int node0 = b * BK_SIZE;

    if (t < BK_SIZE) lcnt[t] = 0;
    __syncthreads();

    for (int j = t; j < cnt; j += 256)
        atomicAdd(&lcnt[pk[base + j] & (BK_SIZE - 1)], 1);
    __syncthreads();

    if (t < BK_SIZE) s[t] = lcnt[t];
    __syncthreads();
    for (int off = 1; off < BK_SIZE; off <<= 1) {
        int u = (t < BK_SIZE && t >= off) ? s[t - off] : 0;
        __syncthreads();
        if (t < BK_SIZE) s[t] += u;
        __syncthreads();
    }
    if (t < BK_SIZE) {
        int excl = s[t] - lcnt[t];
        wcur[t] = excl;
        int node = node0 + t;
        if (node < N) {
            row_start[node] = base + excl;
            row_end[node]   = base + s[t];
        }
    }
    __syncthreads();

    for (int j = t; j < cnt; j += 256) {
        int v = pk[base + j];
        int d = v & (BK_SIZE - 1);
        int pos = atomicAdd(&wcur[d], 1);
        csr_src[base + pos] = v >> BK_SHIFT;
    }
}

// ---------------- gemm1:  Y(bf16) = x@W1l,  C = x@W1r + b1 ----------------
// K=128, F=32. A-tile in LDS; W from global (L1/L2-hot). 4x4 micro-tile.
__global__ __launch_bounds__(256) void gemm1_dual(
    const float* __restrict__ A,
    const float* __restrict__ Wl, const float* __restrict__ Wr,
    const float* __restrict__ b,
    unsigned short* __restrict__ Yb, float* __restrict__ C, int N)
{
    constexpr int K = 128, F = 32, F2 = 64;
    constexpr int JG   = F2 / 4;        // 16
    constexpr int NPB  = (256 / JG) * 4; // 64 nodes/block
    constexpr int APAD = K + 4;

    __shared__ float Asm[NPB * APAD];   // 33.8 KB

    const int tid = threadIdx.x;
    const int node0 = blockIdx.x * NPB;
    constexpr int NF4 = NPB * K / 4;
    for (int f4 = tid; f4 < NF4; f4 += 256) {
        int n  = f4 / (K / 4);
        int kq = f4 % (K / 4);
        int gn = node0 + n;
        float4 v = make_float4(0.f, 0.f, 0.f, 0.f);
        if (gn < N) v = *(const float4*)&A[(size_t)gn * K + kq * 4];
        *(float4*)&Asm[n * APAD + kq * 4] = v;
    }
    __syncthreads();

    const int j0 = (tid % JG) * 4;
    const int n0 = (tid / JG) * 4;
    const bool  isY = (j0 < F);
    const int   jj  = isY ? j0 : (j0 - F);
    const float* Wb = isY ? Wl : Wr;

    float acc[4][4] = {};
    #pragma unroll 2
    for (int k = 0; k < K; k += 4) {
        float4 a0 = *(const float4*)&Asm[(n0 + 0) * APAD + k];
        float4 a1 = *(const float4*)&Asm[(n0 + 1) * APAD + k];
        float4 a2 = *(const float4*)&Asm[(n0 + 2) * APAD + k];
        float4 a3 = *(const float4*)&Asm[(n0 + 3) * APAD + k];
        #pragma unroll
        for (int kk = 0; kk < 4; ++kk) {
            float4 wv = *(const float4*)&Wb[(k + kk) * F + jj];
            float av0 = ((const float*)&a0)[kk];
            float av1 = ((const float*)&a1)[kk];
            float av2 = ((const float*)&a2)[kk];
            float av3 = ((const float*)&a3)[kk];
            acc[0][0] += av0 * wv.x; acc[0][1] += av0 * wv.y;
            acc[0][2] += av0 * wv.z; acc[0][3] += av0 * wv.w;
            acc[1][0] += av1 * wv.x; acc[1][1] += av1 * wv.y;
            acc[1][2] += av1 * wv.z; acc[1][3] += av1 * wv.w;
            acc[2][0] += av2 * wv.x; acc[2][1] += av2 * wv.y;
            acc[2][2] += av2 * wv.z; acc[2][3] += av2 * wv.w;
            acc[3][0] += av3 * wv.x; acc[3][1] += av3 * wv.y;
            acc[3][2] += av3 * wv.z; acc[3][3] += av3 * wv.w;
        }
    }

    if (isY) {
        #pragma unroll
        for (int m = 0; m < 4; ++m) {
            int gn = node0 + n0 + m;
            if (gn < N) {
                ushort4 r;
                r.x = f2bf(acc[m][0]); r.y = f2bf(acc[m][1]);
                r.z = f2bf(acc[m][2]); r.w = f2bf(acc[m][3]);
                *(ushort4*)&Yb[(size_t)gn * F + jj] = r;
            }
        }
    } else {
        float4 bias = *(const float4*)&b[jj];
        #pragma unroll
        for (int m = 0; m < 4; ++m) {
            int gn = node0 + n0 + m;
            if (gn < N) {
                float4 r;
                r.x = acc[m][0] + bias.x;
                r.y = acc[m][1] + bias.y;
                r.z = acc[m][2] + bias.z;
                r.w = acc[m][3] + bias.w;
                *(float4*)&C[(size_t)gn * F + jj] = r;
            }
        }
    }
}

// ------- fused gather1 + relu + gemm2:  h1 = relu(c1 + mean y1[in]);
//         y2 = h1@W2l,  c2 = h1@W2r + b2.   8 lanes per node. -------------
__global__ __launch_bounds__(256) void gather_gemm2(
    const int* __restrict__ row_start, const int* __restrict__ row_end,
    const int* __restrict__ csr_src,
    const unsigned short* __restrict__ Yb,  // y1 bf16 [N][32]
    const float* __restrict__ c1,           // [N][32]
    const float* __restrict__ W2l, const float* __restrict__ W2r,
    const float* __restrict__ b2,
    float* __restrict__ y2, float* __restrict__ c2, int N)
{
    int gid  = blockIdx.x * blockDim.x + threadIdx.x;
    int node = gid >> 3;
    int q    = gid & 7;
    const bool active = node < N;

    float4 acc = make_float4(0.f, 0.f, 0.f, 0.f);
    float h[4] = {0.f, 0.f, 0.f, 0.f};
    if (active) {
        int start = row_start[node];
        int end   = row_end[node];
        float w   = 1.0f / fmaxf((float)(end - start), 1.0f);
        for (int j = start; j < end; ++j) {
            int s = csr_src[j];
            ushort4 v = *(const ushort4*)&Yb[(size_t)s * 32 + q * 4];
            acc.x += bf2f(v.x); acc.y += bf2f(v.y);
            acc.z += bf2f(v.z); acc.w += bf2f(v.w);
        }
        float4 c = *(const float4*)&c1[(size_t)node * 32 + q * 4];
        h[0] = fmaxf(c.x + acc.x * w, 0.f);
        h[1] = fmaxf(c.y + acc.y * w, 0.f);
        h[2] = fmaxf(c.z + acc.z * w, 0.f);
        h[3] = fmaxf(c.w + acc.w * w, 0.f);
    }

    // gemm2 across the 8-lane group: lane q computes outputs j0..j0+3 of [y2|c2]
    const int  j0  = q * 4;
    const bool isY = (j0 < 16);
    const int  jj  = isY ? j0 : (j0 - 16);
    const float* Wb = isY ? W2l : W2r;

    float o0 = 0.f, o1 = 0.f, o2 = 0.f, o3 = 0.f;
    #pragma unroll
    for (int k = 0; k < 32; ++k) {
        float hk = __shfl(h[k & 3], k >> 2, 8);   // broadcast within 8-lane group
        float4 wv = *(const float4*)&Wb[k * 16 + jj];
        o0 += hk * wv.x; o1 += hk * wv.y; o2 += hk * wv.z; o3 += hk * wv.w;
    }

    if (active) {
        if (isY) {
            *(float4*)&y2[(size_t)node * 16 + jj] = make_float4(o0, o1, o2, o3);
        } else {
            float4 bb = *(const float4*)&b2[jj];
            *(float4*)&c2[(size_t)node * 16 + jj] =
                make_float4(o0 + bb.x, o1 + bb.y, o2 + bb.z, o3 + bb.w);
        }
    }
}

// ---------------- fused gather2 + final:  out = relu(c2 + mean)@Wfc + bfc -
__global__ void gather_final(const int* __restrict__ row_start,
                             const int* __restrict__ row_end,
                             const int* __restrict__ csr_src,
                             const float* __restrict__ Y,   // y2 [N][16]
                             const float* __restrict__ c2,  // [N][16]
                             const float* __restrict__ Wfc, // [16][2]
                             const float* __restrict__ bfc, // [2]
                             float* __restrict__ out, int N)
{
    int gid  = blockIdx.x * blockDim.x + threadIdx.x;
    int node = gid / 4;
    int q    = gid % 4;
    if (node >= N) return;

    int start = row_start[node];
    int end   = row_end[node];
    float w   = 1.0f / fmaxf((float)(end - start), 1.0f);

    float4 acc = make_float4(0.f, 0.f, 0.f, 0.f);
    for (int j = start; j < end; ++j) {
        int s = csr_src[j];
        float4 v = *(const float4*)&Y[(size_t)s * 16 + q * 4];
        acc.x += v.x; acc.y += v.y; acc.z += v.z; acc.w += v.w;
    }

    float4 c = *(const float4*)&c2[(size_t)node * 16 + q * 4];
    float h0 = fmaxf(c.x + acc.x * w, 0.f);
    float h1 = fmaxf(c.y + acc.y * w, 0.f);
    float h2 = fmaxf(c.z + acc.z * w, 0.f);
    float h3 = fmaxf(c.w + acc.w * w, 0.f);

    const float* Wq = &Wfc[q * 8];
    float o0 = h0 * Wq[0] + h1 * Wq[2] + h2 * Wq[4] + h3 * Wq[6];
    float o1 = h0 * Wq[1] + h1 * Wq[3] + h2 * Wq[5] + h3 * Wq[7];

    o0 += __shfl_xor(o0, 1); o0 += __shfl_xor(o0, 2);
    o1 += __shfl_xor(o1, 1); o1 += __shfl_xor(o1, 2);

    if (q == 0) ((float2*)out)[node] = make_float2(o0 + bfc[0], o1 + bfc[1]);
}

extern "C" void kernel_launch(void* const* d_in, const int* in_sizes, int n_in,
                              void* d_out, int out_size, void* d_ws, size_t ws_size,
                              hipStream_t stream)
{
    const float* x   = (const float*)d_in[0];
    const int*   ei  = (const int*)d_in[1];   // int32 (JAX default)
    const float* W1l = (const float*)d_in[2];
    const float* b1  = (const float*)d_in[3];
    const float* W1r = (const float*)d_in[4];
    const float* W2l = (const float*)d_in[5];
    const float* b2  = (const float*)d_in[6];
    const float* W2r = (const float*)d_in[7];
    const float* Wfc = (const float*)d_in[8];
    const float* bfc = (const float*)d_in[9];
    float* out = (float*)d_out;

    const int N = in_sizes[0] / 128;
    const int E = in_sizes[1] / 2;
    const int* src = ei;
    const int* dst = ei + E;

    const int NBK = (N + BK_SIZE - 1) / BK_SIZE;   // 782

    int*   bucket_cnt  = (int*)d_ws;                // NBK
    int*   bucket_base = bucket_cnt + NBK_MAX;      // NBK
    int*   gcursor     = bucket_base + NBK_MAX;     // NBK
    int*   row_start   = gcursor + NBK_MAX;         // N
    int*   row_end     = row_start + N;             // N
    int*   csr_src     = row_end + N;               // E
    unsigned short* y1b = (unsigned short*)(csr_src + E);   // N*32 bf16
    float* c1          = (float*)(y1b + (size_t)N * 32);    // N*32
    float* y2          = c1 + (size_t)N * 32;               // N*16
    float* c2          = y2 + (size_t)N * 16;               // N*16
    int*   pk          = (int*)y1b;                 // E ints (dead before gemm1)

    // ---- build CSR (bucketed) ----
    hipMemsetAsync(bucket_cnt, 0, (size_t)NBK * sizeof(int), stream);
    hist_buckets<<<196, 256, 0, stream>>>(dst, bucket_cnt, E, NBK);
    scan_buckets<<<1, 1024, 0, stream>>>(bucket_cnt, bucket_base, gcursor, NBK);
    {
        int nb = (E + 256 * EPT - 1) / (256 * EPT);
        bin_scatter<<<nb, 256, 0, stream>>>(src, dst, gcursor, pk, E, NBK);
    }
    bucket_csr<<<NBK, 256, 0, stream>>>(pk, bucket_base, bucket_cnt,
                                        csr_src, row_start, row_end, N);

    // ---- layer 1 GEMM ----
    gemm1_dual<<<(N + 63) / 64, TPB, 0, stream>>>(
        x, W1l, W1r, b1, y1b, c1, N);

    // ---- fused gather1 + relu + gemm2 ----
    gather_gemm2<<<(N * 8 + TPB - 1) / TPB, TPB, 0, stream>>>(
        row_start, row_end, csr_src, y1b, c1, W2l, W2r, b2, y2, c2, N);

    // ---- fused gather2 + final ----
    gather_final<<<(N * 4 + TPB - 1) / TPB, TPB, 0, stream>>>(
        row_start, row_end, csr_src, y2, c2, Wfc, bfc, out, N);
}

// Round 9
// 244.500 us; speedup vs baseline: 1.1019x; 1.1019x over previous
//
#include <hip/hip_runtime.h>

#define TPB 256
#define BK_SHIFT 7
#define BK_SIZE 128
#define NBK_MAX 800     // >= ceil(100000/128)=782
#define EPT 32          // edges per thread in bin_scatter chunks

__device__ __forceinline__ unsigned short f2bf(float f) {
    unsigned u = __float_as_uint(f);
    unsigned r = (u + 0x7FFFu + ((u >> 16) & 1u)) >> 16;   // RNE
    return (unsigned short)r;
}
__device__ __forceinline__ float bf2f(unsigned short b) {
    return __uint_as_float((unsigned)b << 16);
}

// ---------------- bucket histogram (LDS-privatized, int4 loads) -----------
__global__ __launch_bounds__(256) void hist_buckets(
    const int* __restrict__ dst, int* __restrict__ bcnt, int E, int NBK)
{
    __shared__ int h[NBK_MAX];
    const int t = threadIdx.x;
    for (int i = t; i < NBK; i += 256) h[i] = 0;
    __syncthreads();
    const int E4 = E >> 2;
    for (int e4 = blockIdx.x * blockDim.x + t; e4 < E4; e4 += gridDim.x * blockDim.x) {
        int4 d = ((const int4*)dst)[e4];
        atomicAdd(&h[d.x >> BK_SHIFT], 1);
        atomicAdd(&h[d.y >> BK_SHIFT], 1);
        atomicAdd(&h[d.z >> BK_SHIFT], 1);
        atomicAdd(&h[d.w >> BK_SHIFT], 1);
    }
    if (blockIdx.x == 0) {
        for (int e = E4 * 4 + t; e < E; e += 256)
            atomicAdd(&h[dst[e] >> BK_SHIFT], 1);
    }
    __syncthreads();
    for (int i = t; i < NBK; i += 256)
        if (h[i]) atomicAdd(&bcnt[i], h[i]);
}

// ---------------- scan of bucket counts (one block, NBK<=1024) ------------
__global__ __launch_bounds__(1024) void scan_buckets(
    const int* __restrict__ bcnt, int* __restrict__ bbase,
    int* __restrict__ gcursor, int NBK)
{
    __shared__ int s[1024];
    const int t = threadIdx.x;
    int v = (t < NBK) ? bcnt[t] : 0;
    s[t] = v;
    __syncthreads();
    for (int off = 1; off < 1024; off <<= 1) {
        int u = (t >= off) ? s[t - off] : 0;
        __syncthreads();
        s[t] += u;
        __syncthreads();
    }
    if (t < NBK) {
        int excl = s[t] - v;
        bbase[t]   = excl;
        gcursor[t] = excl;
    }
}

// ---------------- bin scatter: pack edges into bucket-ordered pk[] --------
__global__ __launch_bounds__(256) void bin_scatter(
    const int* __restrict__ src, const int* __restrict__ dst,
    int* __restrict__ gcursor, int* __restrict__ pk, int E, int NBK)
{
    __shared__ int lcnt[NBK_MAX];
    __shared__ int lbase[NBK_MAX];
    __shared__ int lrank[NBK_MAX];
    const int t = threadIdx.x;
    const int e0 = blockIdx.x * (256 * EPT);

    for (int i = t; i < NBK; i += 256) { lcnt[i] = 0; lrank[i] = 0; }
    __syncthreads();

    #pragma unroll 4
    for (int k = 0; k < EPT; ++k) {
        int e = e0 + k * 256 + t;
        if (e < E) atomicAdd(&lcnt[dst[e] >> BK_SHIFT], 1);
    }
    __syncthreads();

    for (int i = t; i < NBK; i += 256) {
        int c = lcnt[i];
        if (c) lbase[i] = atomicAdd(&gcursor[i], c);
    }
    __syncthreads();

    #pragma unroll 4
    for (int k = 0; k < EPT; ++k) {
        int e = e0 + k * 256 + t;
        if (e < E) {
            int d = dst[e], s = src[e];
            int b = d >> BK_SHIFT;
            int r = atomicAdd(&lrank[b], 1);
            pk[lbase[b] + r] = (s << BK_SHIFT) | (d & (BK_SIZE - 1));
        }
    }
}

// ---------------- per-bucket counting sort -> exact CSR -------------------
__global__ __launch_bounds__(256) void bucket_csr(
    const int* __restrict__ pk, const int* __restrict__ bbase,
    const int* __restrict__ bcnt,
    int* __restrict__ csr_src, int* __restrict__ row_start,
    int* __restrict__ row_end, int N)
{
    __shared__ int lcnt[BK_SIZE];
    __shared__ int s[BK_SIZE];
    __shared__ int wcur[BK_SIZE];
    const int t = threadIdx.x;
    const int b = blockIdx.x;
    const int base = bbase[b];
    const int cnt  = bcnt[b];
    const int node0 = b * BK_SIZE;

    if (t < BK_SIZE) lcnt[t] = 0;
    __syncthreads();

    for (int j = t; j < cnt; j += 256)
        atomicAdd(&lcnt[pk[base + j] & (BK_SIZE - 1)], 1);
    __syncthreads();

    if (t < BK_SIZE) s[t] = lcnt[t];
    __syncthreads();
    for (int off = 1; off < BK_SIZE; off <<= 1) {
        int u = (t < BK_SIZE && t >= off) ? s[t - off] : 0;
        __syncthreads();
        if (t < BK_SIZE) s[t] += u;
        __syncthreads();
    }
    if (t < BK_SIZE) {
        int excl = s[t] - lcnt[t];
        wcur[t] = excl;
        int node = node0 + t;
        if (node < N) {
            row_start[node] = base + excl;
            row_end[node]   = base + s[t];
        }
    }
    __syncthreads();

    for (int j = t; j < cnt; j += 256) {
        int v = pk[base + j];
        int d = v & (BK_SIZE - 1);
        int pos = atomicAdd(&wcur[d], 1);
        csr_src[base + pos] = v >> BK_SHIFT;
    }
}

// ---------------- gemm1:  Y(bf16) = x@W1l,  C = x@W1r + b1 ----------------
__global__ __launch_bounds__(256) void gemm1_dual(
    const float* __restrict__ A,
    const float* __restrict__ Wl, const float* __restrict__ Wr,
    const float* __restrict__ b,
    unsigned short* __restrict__ Yb, float* __restrict__ C, int N)
{
    constexpr int K = 128, F = 32, F2 = 64;
    constexpr int JG   = F2 / 4;         // 16
    constexpr int NPB  = (256 / JG) * 4; // 64 nodes/block
    constexpr int APAD = K + 4;

    __shared__ float Asm[NPB * APAD];   // 33.8 KB

    const int tid = threadIdx.x;
    const int node0 = blockIdx.x * NPB;
    constexpr int NF4 = NPB * K / 4;
    for (int f4 = tid; f4 < NF4; f4 += 256) {
        int n  = f4 / (K / 4);
        int kq = f4 % (K / 4);
        int gn = node0 + n;
        float4 v = make_float4(0.f, 0.f, 0.f, 0.f);
        if (gn < N) v = *(const float4*)&A[(size_t)gn * K + kq * 4];
        *(float4*)&Asm[n * APAD + kq * 4] = v;
    }
    __syncthreads();

    const int j0 = (tid % JG) * 4;
    const int n0 = (tid / JG) * 4;
    const bool  isY = (j0 < F);
    const int   jj  = isY ? j0 : (j0 - F);
    const float* Wb = isY ? Wl : Wr;

    float acc[4][4] = {};
    #pragma unroll 2
    for (int k = 0; k < K; k += 4) {
        float4 a0 = *(const float4*)&Asm[(n0 + 0) * APAD + k];
        float4 a1 = *(const float4*)&Asm[(n0 + 1) * APAD + k];
        float4 a2 = *(const float4*)&Asm[(n0 + 2) * APAD + k];
        float4 a3 = *(const float4*)&Asm[(n0 + 3) * APAD + k];
        #pragma unroll
        for (int kk = 0; kk < 4; ++kk) {
            float4 wv = *(const float4*)&Wb[(k + kk) * F + jj];
            float av0 = ((const float*)&a0)[kk];
            float av1 = ((const float*)&a1)[kk];
            float av2 = ((const float*)&a2)[kk];
            float av3 = ((const float*)&a3)[kk];
            acc[0][0] += av0 * wv.x; acc[0][1] += av0 * wv.y;
            acc[0][2] += av0 * wv.z; acc[0][3] += av0 * wv.w;
            acc[1][0] += av1 * wv.x; acc[1][1] += av1 * wv.y;
            acc[1][2] += av1 * wv.z; acc[1][3] += av1 * wv.w;
            acc[2][0] += av2 * wv.x; acc[2][1] += av2 * wv.y;
            acc[2][2] += av2 * wv.z; acc[2][3] += av2 * wv.w;
            acc[3][0] += av3 * wv.x; acc[3][1] += av3 * wv.y;
            acc[3][2] += av3 * wv.z; acc[3][3] += av3 * wv.w;
        }
    }

    if (isY) {
        #pragma unroll
        for (int m = 0; m < 4; ++m) {
            int gn = node0 + n0 + m;
            if (gn < N) {
                ushort4 r;
                r.x = f2bf(acc[m][0]); r.y = f2bf(acc[m][1]);
                r.z = f2bf(acc[m][2]); r.w = f2bf(acc[m][3]);
                *(ushort4*)&Yb[(size_t)gn * F + jj] = r;
            }
        }
    } else {
        float4 bias = *(const float4*)&b[jj];
        #pragma unroll
        for (int m = 0; m < 4; ++m) {
            int gn = node0 + n0 + m;
            if (gn < N) {
                float4 r;
                r.x = acc[m][0] + bias.x;
                r.y = acc[m][1] + bias.y;
                r.z = acc[m][2] + bias.z;
                r.w = acc[m][3] + bias.w;
                *(float4*)&C[(size_t)gn * F + jj] = r;
            }
        }
    }
}

// ------- fused gather1 + relu + gemm2 (4x-unrolled gather for MLP) --------
// h1 = relu(c1 + mean y1[in]); y2(bf16) = h1@W2l, c2 = h1@W2r + b2.
__global__ __launch_bounds__(256) void gather_gemm2(
    const int* __restrict__ row_start, const int* __restrict__ row_end,
    const int* __restrict__ csr_src,
    const unsigned short* __restrict__ Yb,  // y1 bf16 [N][32]
    const float* __restrict__ c1,           // [N][32]
    const float* __restrict__ W2l, const float* __restrict__ W2r,
    const float* __restrict__ b2,
    unsigned short* __restrict__ y2b, float* __restrict__ c2, int N)
{
    int gid  = blockIdx.x * blockDim.x + threadIdx.x;
    int node = gid >> 3;
    int q    = gid & 7;
    const bool active = node < N;

    float h[4] = {0.f, 0.f, 0.f, 0.f};
    if (active) {
        int start = row_start[node];
        int end   = row_end[node];
        float w   = 1.0f / fmaxf((float)(end - start), 1.0f);

        float4 a0 = make_float4(0.f, 0.f, 0.f, 0.f);
        float4 a1 = make_float4(0.f, 0.f, 0.f, 0.f);
        float4 a2 = make_float4(0.f, 0.f, 0.f, 0.f);
        float4 a3 = make_float4(0.f, 0.f, 0.f, 0.f);
        int j = start;
        for (; j + 3 < end; j += 4) {
            int s0 = csr_src[j];
            int s1 = csr_src[j + 1];
            int s2 = csr_src[j + 2];
            int s3 = csr_src[j + 3];
            ushort4 v0 = *(const ushort4*)&Yb[(size_t)s0 * 32 + q * 4];
            ushort4 v1 = *(const ushort4*)&Yb[(size_t)s1 * 32 + q * 4];
            ushort4 v2 = *(const ushort4*)&Yb[(size_t)s2 * 32 + q * 4];
            ushort4 v3 = *(const ushort4*)&Yb[(size_t)s3 * 32 + q * 4];
            a0.x += bf2f(v0.x); a0.y += bf2f(v0.y); a0.z += bf2f(v0.z); a0.w += bf2f(v0.w);
            a1.x += bf2f(v1.x); a1.y += bf2f(v1.y); a1.z += bf2f(v1.z); a1.w += bf2f(v1.w);
            a2.x += bf2f(v2.x); a2.y += bf2f(v2.y); a2.z += bf2f(v2.z); a2.w += bf2f(v2.w);
            a3.x += bf2f(v3.x); a3.y += bf2f(v3.y); a3.z += bf2f(v3.z); a3.w += bf2f(v3.w);
        }
        for (; j < end; ++j) {
            int s = csr_src[j];
            ushort4 v = *(const ushort4*)&Yb[(size_t)s * 32 + q * 4];
            a0.x += bf2f(v.x); a0.y += bf2f(v.y); a0.z += bf2f(v.z); a0.w += bf2f(v.w);
        }
        float4 acc;
        acc.x = (a0.x + a1.x) + (a2.x + a3.x);
        acc.y = (a0.y + a1.y) + (a2.y + a3.y);
        acc.z = (a0.z + a1.z) + (a2.z + a3.z);
        acc.w = (a0.w + a1.w) + (a2.w + a3.w);

        float4 c = *(const float4*)&c1[(size_t)node * 32 + q * 4];
        h[0] = fmaxf(c.x + acc.x * w, 0.f);
        h[1] = fmaxf(c.y + acc.y * w, 0.f);
        h[2] = fmaxf(c.z + acc.z * w, 0.f);
        h[3] = fmaxf(c.w + acc.w * w, 0.f);
    }

    // gemm2 across the 8-lane group: lane q computes outputs j0..j0+3 of [y2|c2]
    const int  j0  = q * 4;
    const bool isY = (j0 < 16);
    const int  jj  = isY ? j0 : (j0 - 16);
    const float* Wb = isY ? W2l : W2r;

    float o0 = 0.f, o1 = 0.f, o2 = 0.f, o3 = 0.f;
    #pragma unroll
    for (int k = 0; k < 32; ++k) {
        float hk = __shfl(h[k & 3], k >> 2, 8);   // broadcast within 8-lane group
        float4 wv = *(const float4*)&Wb[k * 16 + jj];
        o0 += hk * wv.x; o1 += hk * wv.y; o2 += hk * wv.z; o3 += hk * wv.w;
    }

    if (active) {
        if (isY) {
            ushort4 r;
            r.x = f2bf(o0); r.y = f2bf(o1); r.z = f2bf(o2); r.w = f2bf(o3);
            *(ushort4*)&y2b[(size_t)node * 16 + jj] = r;
        } else {
            float4 bb = *(const float4*)&b2[jj];
            *(float4*)&c2[(size_t)node * 16 + jj] =
                make_float4(o0 + bb.x, o1 + bb.y, o2 + bb.z, o3 + bb.w);
        }
    }
}

// ------- fused gather2 + final (4x-unrolled):  out = relu(c2+mean)@Wfc+bfc
__global__ __launch_bounds__(256) void gather_final(
    const int* __restrict__ row_start, const int* __restrict__ row_end,
    const int* __restrict__ csr_src,
    const unsigned short* __restrict__ Yb,  // y2 bf16 [N][16]
    const float* __restrict__ c2,           // [N][16]
    const float* __restrict__ Wfc,          // [16][2]
    const float* __restrict__ bfc,          // [2]
    float* __restrict__ out, int N)
{
    int gid  = blockIdx.x * blockDim.x + threadIdx.x;
    int node = gid >> 2;
    int q    = gid & 3;
    if (node >= N) return;

    int start = row_start[node];
    int end   = row_end[node];
    float w   = 1.0f / fmaxf((float)(end - start), 1.0f);

    float4 a0 = make_float4(0.f, 0.f, 0.f, 0.f);
    float4 a1 = make_float4(0.f, 0.f, 0.f, 0.f);
    float4 a2 = make_float4(0.f, 0.f, 0.f, 0.f);
    float4 a3 = make_float4(0.f, 0.f, 0.f, 0.f);
    int j = start;
    for (; j + 3 < end; j += 4) {
        int s0 = csr_src[j];
        int s1 = csr_src[j + 1];
        int s2 = csr_src[j + 2];
        int s3 = csr_src[j + 3];
        ushort4 v0 = *(const ushort4*)&Yb[(size_t)s0 * 16 + q * 4];
        ushort4 v1 = *(const ushort4*)&Yb[(size_t)s1 * 16 + q * 4];
        ushort4 v2 = *(const ushort4*)&Yb[(size_t)s2 * 16 + q * 4];
        ushort4 v3 = *(const ushort4*)&Yb[(size_t)s3 * 16 + q * 4];
        a0.x += bf2f(v0.x); a0.y += bf2f(v0.y); a0.z += bf2f(v0.z); a0.w += bf2f(v0.w);
        a1.x += bf2f(v1.x); a1.y += bf2f(v1.y); a1.z += bf2f(v1.z); a1.w += bf2f(v1.w);
        a2.x += bf2f(v2.x); a2.y += bf2f(v2.y); a2.z += bf2f(v2.z); a2.w += bf2f(v2.w);
        a3.x += bf2f(v3.x); a3.y += bf2f(v3.y); a3.z += bf2f(v3.z); a3.w += bf2f(v3.w);
    }
    for (; j < end; ++j) {
        int s = csr_src[j];
        ushort4 v = *(const ushort4*)&Yb[(size_t)s * 16 + q * 4];
        a0.x += bf2f(v.x); a0.y += bf2f(v.y); a0.z += bf2f(v.z); a0.w += bf2f(v.w);
    }
    float4 acc;
    acc.x = (a0.x + a1.x) + (a2.x + a3.x);
    acc.y = (a0.y + a1.y) + (a2.y + a3.y);
    acc.z = (a0.z + a1.z) + (a2.z + a3.z);
    acc.w = (a0.w + a1.w) + (a2.w + a3.w);

    float4 c = *(const float4*)&c2[(size_t)node * 16 + q * 4];
    float h0 = fmaxf(c.x + acc.x * w, 0.f);
    float h1 = fmaxf(c.y + acc.y * w, 0.f);
    float h2 = fmaxf(c.z + acc.z * w, 0.f);
    float h3 = fmaxf(c.w + acc.w * w, 0.f);

    const float* Wq = &Wfc[q * 8];
    float o0 = h0 * Wq[0] + h1 * Wq[2] + h2 * Wq[4] + h3 * Wq[6];
    float o1 = h0 * Wq[1] + h1 * Wq[3] + h2 * Wq[5] + h3 * Wq[7];

    o0 += __shfl_xor(o0, 1); o0 += __shfl_xor(o0, 2);
    o1 += __shfl_xor(o1, 1); o1 += __shfl_xor(o1, 2);

    if (q == 0) ((float2*)out)[node] = make_float2(o0 + bfc[0], o1 + bfc[1]);
}

extern "C" void kernel_launch(void* const* d_in, const int* in_sizes, int n_in,
                              void* d_out, int out_size, void* d_ws, size_t ws_size,
                              hipStream_t stream)
{
    const float* x   = (const float*)d_in[0];
    const int*   ei  = (const int*)d_in[1];   // int32 (JAX default)
    const float* W1l = (const float*)d_in[2];
    const float* b1  = (const float*)d_in[3];
    const float* W1r = (const float*)d_in[4];
    const float* W2l = (const float*)d_in[5];
    const float* b2  = (const float*)d_in[6];
    const float* W2r = (const float*)d_in[7];
    const float* Wfc = (const float*)d_in[8];
    const float* bfc = (const float*)d_in[9];
    float* out = (float*)d_out;

    const int N = in_sizes[0] / 128;
    const int E = in_sizes[1] / 2;
    const int* src = ei;
    const int* dst = ei + E;

    const int NBK = (N + BK_SIZE - 1) / BK_SIZE;   // 782

    int*   bucket_cnt  = (int*)d_ws;                // NBK
    int*   bucket_base = bucket_cnt + NBK_MAX;      // NBK
    int*   gcursor     = bucket_base + NBK_MAX;     // NBK
    int*   row_start   = gcursor + NBK_MAX;         // N
    int*   row_end     = row_start + N;             // N
    int*   csr_src     = row_end + N;               // E
    unsigned short* y1b = (unsigned short*)(csr_src + E);   // N*32 bf16
    float* c1          = (float*)(y1b + (size_t)N * 32);    // N*32 f32
    unsigned short* y2b = (unsigned short*)(c1 + (size_t)N * 32); // N*16 bf16
    float* c2          = (float*)(y2b + (size_t)N * 16);    // N*16 f32
    int*   pk          = (int*)y1b;                 // E ints (dead before gemm1)

    // ---- build CSR (bucketed) ----
    hipMemsetAsync(bucket_cnt, 0, (size_t)NBK * sizeof(int), stream);
    hist_buckets<<<196, 256, 0, stream>>>(dst, bucket_cnt, E, NBK);
    scan_buckets<<<1, 1024, 0, stream>>>(bucket_cnt, bucket_base, gcursor, NBK);
    {
        int nb = (E + 256 * EPT - 1) / (256 * EPT);
        bin_scatter<<<nb, 256, 0, stream>>>(src, dst, gcursor, pk, E, NBK);
    }
    bucket_csr<<<NBK, 256, 0, stream>>>(pk, bucket_base, bucket_cnt,
                                        csr_src, row_start, row_end, N);

    // ---- layer 1 GEMM ----
    gemm1_dual<<<(N + 63) / 64, TPB, 0, stream>>>(
        x, W1l, W1r, b1, y1b, c1, N);

    // ---- fused gather1 + relu + gemm2 ----
    gather_gemm2<<<(N * 8 + TPB - 1) / TPB, TPB, 0, stream>>>(
        row_start, row_end, csr_src, y1b, c1, W2l, W2r, b2, y2b, c2, N);

    // ---- fused gather2 + final ----
    gather_final<<<(N * 4 + TPB - 1) / TPB, TPB, 0, stream>>>(
        row_start, row_end, csr_src, y2b, c2, Wfc, bfc, out, N);
}

// Round 10
// 221.895 us; speedup vs baseline: 1.2142x; 1.1019x over previous
//
#include <hip/hip_runtime.h>

#define TPB 256
#define BK_SHIFT 7
#define BK_SIZE 128
#define NBK_MAX 800     // >= ceil(100000/128)=782
#define EPT 32          // edges per thread in bin_scatter chunks

typedef __attribute__((ext_vector_type(8))) short bf16x8;
typedef __attribute__((ext_vector_type(4))) float f32x4;

__device__ __forceinline__ unsigned short f2bf(float f) {
    unsigned u = __float_as_uint(f);
    unsigned r = (u + 0x7FFFu + ((u >> 16) & 1u)) >> 16;   // RNE
    return (unsigned short)r;
}
__device__ __forceinline__ float bf2f(unsigned short b) {
    return __uint_as_float((unsigned)b << 16);
}

// ---------------- bucket histogram (LDS-privatized, int4 loads) -----------
__global__ __launch_bounds__(256) void hist_buckets(
    const int* __restrict__ dst, int* __restrict__ bcnt, int E, int NBK)
{
    __shared__ int h[NBK_MAX];
    const int t = threadIdx.x;
    for (int i = t; i < NBK; i += 256) h[i] = 0;
    __syncthreads();
    const int E4 = E >> 2;
    for (int e4 = blockIdx.x * blockDim.x + t; e4 < E4; e4 += gridDim.x * blockDim.x) {
        int4 d = ((const int4*)dst)[e4];
        atomicAdd(&h[d.x >> BK_SHIFT], 1);
        atomicAdd(&h[d.y >> BK_SHIFT], 1);
        atomicAdd(&h[d.z >> BK_SHIFT], 1);
        atomicAdd(&h[d.w >> BK_SHIFT], 1);
    }
    if (blockIdx.x == 0) {
        for (int e = E4 * 4 + t; e < E; e += 256)
            atomicAdd(&h[dst[e] >> BK_SHIFT], 1);
    }
    __syncthreads();
    for (int i = t; i < NBK; i += 256)
        if (h[i]) atomicAdd(&bcnt[i], h[i]);
}

// ---------------- scan of bucket counts (one block, NBK<=1024) ------------
__global__ __launch_bounds__(1024) void scan_buckets(
    const int* __restrict__ bcnt, int* __restrict__ bbase,
    int* __restrict__ gcursor, int NBK)
{
    __shared__ int s[1024];
    const int t = threadIdx.x;
    int v = (t < NBK) ? bcnt[t] : 0;
    s[t] = v;
    __syncthreads();
    for (int off = 1; off < 1024; off <<= 1) {
        int u = (t >= off) ? s[t - off] : 0;
        __syncthreads();
        s[t] += u;
        __syncthreads();
    }
    if (t < NBK) {
        int excl = s[t] - v;
        bbase[t]   = excl;
        gcursor[t] = excl;
    }
}

// ---------------- bin scatter: pack edges into bucket-ordered pk[] --------
__global__ __launch_bounds__(256) void bin_scatter(
    const int* __restrict__ src, const int* __restrict__ dst,
    int* __restrict__ gcursor, int* __restrict__ pk, int E, int NBK)
{
    __shared__ int lcnt[NBK_MAX];
    __shared__ int lbase[NBK_MAX];
    __shared__ int lrank[NBK_MAX];
    const int t = threadIdx.x;
    const int e0 = blockIdx.x * (256 * EPT);

    for (int i = t; i < NBK; i += 256) { lcnt[i] = 0; lrank[i] = 0; }
    __syncthreads();

    #pragma unroll 4
    for (int k = 0; k < EPT; ++k) {
        int e = e0 + k * 256 + t;
        if (e < E) atomicAdd(&lcnt[dst[e] >> BK_SHIFT], 1);
    }
    __syncthreads();

    for (int i = t; i < NBK; i += 256) {
        int c = lcnt[i];
        if (c) lbase[i] = atomicAdd(&gcursor[i], c);
    }
    __syncthreads();

    #pragma unroll 4
    for (int k = 0; k < EPT; ++k) {
        int e = e0 + k * 256 + t;
        if (e < E) {
            int d = dst[e], s = src[e];
            int b = d >> BK_SHIFT;
            int r = atomicAdd(&lrank[b], 1);
            pk[lbase[b] + r] = (s << BK_SHIFT) | (d & (BK_SIZE - 1));
        }
    }
}

// ---------------- per-bucket counting sort -> exact CSR -------------------
__global__ __launch_bounds__(256) void bucket_csr(
    const int* __restrict__ pk, const int* __restrict__ bbase,
    const int* __restrict__ bcnt,
    int* __restrict__ csr_src, int* __restrict__ row_start,
    int* __restrict__ row_end, int N)
{
    __shared__ int lcnt[BK_SIZE];
    __shared__ int s[BK_SIZE];
    __shared__ int wcur[BK_SIZE];
    const int t = threadIdx.x;
    const int b = blockIdx.x;
    const int base = bbase[b];
    const int cnt  = bcnt[b];
    const int node0 = b * BK_SIZE;

    if (t < BK_SIZE) lcnt[t] = 0;
    __syncthreads();

    for (int j = t; j < cnt; j += 256)
        atomicAdd(&lcnt[pk[base + j] & (BK_SIZE - 1)], 1);
    __syncthreads();

    if (t < BK_SIZE) s[t] = lcnt[t];
    __syncthreads();
    for (int off = 1; off < BK_SIZE; off <<= 1) {
        int u = (t < BK_SIZE && t >= off) ? s[t - off] : 0;
        __syncthreads();
        if (t < BK_SIZE) s[t] += u;
        __syncthreads();
    }
    if (t < BK_SIZE) {
        int excl = s[t] - lcnt[t];
        wcur[t] = excl;
        int node = node0 + t;
        if (node < N) {
            row_start[node] = base + excl;
            row_end[node]   = base + s[t];
        }
    }
    __syncthreads();

    for (int j = t; j < cnt; j += 256) {
        int v = pk[base + j];
        int d = v & (BK_SIZE - 1);
        int pos = atomicAdd(&wcur[d], 1);
        csr_src[base + pos] = v >> BK_SHIFT;
    }
}

// ---------------- gemm1 via MFMA:  y1(bf16)=x@W1l,  c1=x@W1r+b1 -----------
// One wave = one 16-node tile (grid-stride). 16x16x32 bf16 MFMA.
// Fragment layouts (m89/m91-verified):
//   A[m=lane&15][k=quad*8+j],  B[k=quad*8+j][n=lane&15],
//   D[row=quad*4+reg][col=lane&15].
__global__ __launch_bounds__(256) void gemm1_mfma(
    const float* __restrict__ A,      // x [N][128]
    const float* __restrict__ Wl,     // [128][32]
    const float* __restrict__ Wr,     // [128][32]
    const float* __restrict__ b,      // [32]
    unsigned short* __restrict__ Yb,  // y1 bf16 [N][32]
    float* __restrict__ C,            // c1 [N][32]
    int N)
{
    const int lane = threadIdx.x & 63;
    const int m    = lane & 15;
    const int quad = lane >> 4;
    const int wave   = blockIdx.x * (blockDim.x >> 6) + (threadIdx.x >> 6);
    const int nwaves = gridDim.x * (blockDim.x >> 6);
    const int ntiles = (N + 15) >> 4;

    // ---- preload B fragments (amortized over the tile loop; L1-hot) ----
    bf16x8 Bf[4][4];   // [kc][jt]; jt 0,1 -> Wl cols 0..31; jt 2,3 -> Wr
    #pragma unroll
    for (int kc = 0; kc < 4; ++kc) {
        #pragma unroll
        for (int jt = 0; jt < 4; ++jt) {
            const float* W = (jt < 2) ? Wl : Wr;
            const int col = (jt & 1) * 16 + m;
            #pragma unroll
            for (int j = 0; j < 8; ++j) {
                int k = kc * 32 + quad * 8 + j;
                Bf[kc][jt][j] = (short)f2bf(W[k * 32 + col]);
            }
        }
    }

    const float bias0 = b[m];
    const float bias1 = b[16 + m];

    for (int tile = wave; tile < ntiles; tile += nwaves) {
        const int node0 = tile * 16;
        const int gn = node0 + m;
        const bool okA = gn < N;
        const float* rowp = A + (size_t)gn * 128;

        bf16x8 Af[4];
        #pragma unroll
        for (int kc = 0; kc < 4; ++kc) {
            float4 v0 = make_float4(0.f, 0.f, 0.f, 0.f);
            float4 v1 = make_float4(0.f, 0.f, 0.f, 0.f);
            if (okA) {
                v0 = *(const float4*)&rowp[kc * 32 + quad * 8];
                v1 = *(const float4*)&rowp[kc * 32 + quad * 8 + 4];
            }
            Af[kc][0] = (short)f2bf(v0.x); Af[kc][1] = (short)f2bf(v0.y);
            Af[kc][2] = (short)f2bf(v0.z); Af[kc][3] = (short)f2bf(v0.w);
            Af[kc][4] = (short)f2bf(v1.x); Af[kc][5] = (short)f2bf(v1.y);
            Af[kc][6] = (short)f2bf(v1.z); Af[kc][7] = (short)f2bf(v1.w);
        }

        f32x4 acc[4] = {{0.f,0.f,0.f,0.f},{0.f,0.f,0.f,0.f},
                        {0.f,0.f,0.f,0.f},{0.f,0.f,0.f,0.f}};
        #pragma unroll
        for (int kc = 0; kc < 4; ++kc) {
            #pragma unroll
            for (int jt = 0; jt < 4; ++jt)
                acc[jt] = __builtin_amdgcn_mfma_f32_16x16x32_bf16(
                    Af[kc], Bf[kc][jt], acc[jt], 0, 0, 0);
        }

        const int nodeBase = node0 + quad * 4;
        #pragma unroll
        for (int reg = 0; reg < 4; ++reg) {
            const int node = nodeBase + reg;
            if (node < N) {
                Yb[(size_t)node * 32 + m]      = f2bf(acc[0][reg]);
                Yb[(size_t)node * 32 + 16 + m] = f2bf(acc[1][reg]);
                C [(size_t)node * 32 + m]      = acc[2][reg] + bias0;
                C [(size_t)node * 32 + 16 + m] = acc[3][reg] + bias1;
            }
        }
    }
}

// ------- fused gather1 + relu + gemm2 (4x-unrolled gather for MLP) --------
__global__ __launch_bounds__(256) void gather_gemm2(
    const int* __restrict__ row_start, const int* __restrict__ row_end,
    const int* __restrict__ csr_src,
    const unsigned short* __restrict__ Yb,  // y1 bf16 [N][32]
    const float* __restrict__ c1,           // [N][32]
    const float* __restrict__ W2l, const float* __restrict__ W2r,
    const float* __restrict__ b2,
    unsigned short* __restrict__ y2b, float* __restrict__ c2, int N)
{
    int gid  = blockIdx.x * blockDim.x + threadIdx.x;
    int node = gid >> 3;
    int q    = gid & 7;
    const bool active = node < N;

    float h[4] = {0.f, 0.f, 0.f, 0.f};
    if (active) {
        int start = row_start[node];
        int end   = row_end[node];
        float w   = 1.0f / fmaxf((float)(end - start), 1.0f);

        float4 a0 = make_float4(0.f, 0.f, 0.f, 0.f);
        float4 a1 = make_float4(0.f, 0.f, 0.f, 0.f);
        float4 a2 = make_float4(0.f, 0.f, 0.f, 0.f);
        float4 a3 = make_float4(0.f, 0.f, 0.f, 0.f);
        int j = start;
        for (; j + 3 < end; j += 4) {
            int s0 = csr_src[j];
            int s1 = csr_src[j + 1];
            int s2 = csr_src[j + 2];
            int s3 = csr_src[j + 3];
            ushort4 v0 = *(const ushort4*)&Yb[(size_t)s0 * 32 + q * 4];
            ushort4 v1 = *(const ushort4*)&Yb[(size_t)s1 * 32 + q * 4];
            ushort4 v2 = *(const ushort4*)&Yb[(size_t)s2 * 32 + q * 4];
            ushort4 v3 = *(const ushort4*)&Yb[(size_t)s3 * 32 + q * 4];
            a0.x += bf2f(v0.x); a0.y += bf2f(v0.y); a0.z += bf2f(v0.z); a0.w += bf2f(v0.w);
            a1.x += bf2f(v1.x); a1.y += bf2f(v1.y); a1.z += bf2f(v1.z); a1.w += bf2f(v1.w);
            a2.x += bf2f(v2.x); a2.y += bf2f(v2.y); a2.z += bf2f(v2.z); a2.w += bf2f(v2.w);
            a3.x += bf2f(v3.x); a3.y += bf2f(v3.y); a3.z += bf2f(v3.z); a3.w += bf2f(v3.w);
        }
        for (; j < end; ++j) {
            int s = csr_src[j];
            ushort4 v = *(const ushort4*)&Yb[(size_t)s * 32 + q * 4];
            a0.x += bf2f(v.x); a0.y += bf2f(v.y); a0.z += bf2f(v.z); a0.w += bf2f(v.w);
        }
        float4 acc;
        acc.x = (a0.x + a1.x) + (a2.x + a3.x);
        acc.y = (a0.y + a1.y) + (a2.y + a3.y);
        acc.z = (a0.z + a1.z) + (a2.z + a3.z);
        acc.w = (a0.w + a1.w) + (a2.w + a3.w);

        float4 c = *(const float4*)&c1[(size_t)node * 32 + q * 4];
        h[0] = fmaxf(c.x + acc.x * w, 0.f);
        h[1] = fmaxf(c.y + acc.y * w, 0.f);
        h[2] = fmaxf(c.z + acc.z * w, 0.f);
        h[3] = fmaxf(c.w + acc.w * w, 0.f);
    }

    const int  j0  = q * 4;
    const bool isY = (j0 < 16);
    const int  jj  = isY ? j0 : (j0 - 16);
    const float* Wb = isY ? W2l : W2r;

    float o0 = 0.f, o1 = 0.f, o2 = 0.f, o3 = 0.f;
    #pragma unroll
    for (int k = 0; k < 32; ++k) {
        float hk = __shfl(h[k & 3], k >> 2, 8);
        float4 wv = *(const float4*)&Wb[k * 16 + jj];
        o0 += hk * wv.x; o1 += hk * wv.y; o2 += hk * wv.z; o3 += hk * wv.w;
    }

    if (active) {
        if (isY) {
            ushort4 r;
            r.x = f2bf(o0); r.y = f2bf(o1); r.z = f2bf(o2); r.w = f2bf(o3);
            *(ushort4*)&y2b[(size_t)node * 16 + jj] = r;
        } else {
            float4 bb = *(const float4*)&b2[jj];
            *(float4*)&c2[(size_t)node * 16 + jj] =
                make_float4(o0 + bb.x, o1 + bb.y, o2 + bb.z, o3 + bb.w);
        }
    }
}

// ------- fused gather2 + final (4x-unrolled):  out = relu(c2+mean)@Wfc+bfc
__global__ __launch_bounds__(256) void gather_final(
    const int* __restrict__ row_start, const int* __restrict__ row_end,
    const int* __restrict__ csr_src,
    const unsigned short* __restrict__ Yb,  // y2 bf16 [N][16]
    const float* __restrict__ c2,           // [N][16]
    const float* __restrict__ Wfc,          // [16][2]
    const float* __restrict__ bfc,          // [2]
    float* __restrict__ out, int N)
{
    int gid  = blockIdx.x * blockDim.x + threadIdx.x;
    int node = gid >> 2;
    int q    = gid & 3;
    if (node >= N) return;

    int start = row_start[node];
    int end   = row_end[node];
    float w   = 1.0f / fmaxf((float)(end - start), 1.0f);

    float4 a0 = make_float4(0.f, 0.f, 0.f, 0.f);
    float4 a1 = make_float4(0.f, 0.f, 0.f, 0.f);
    float4 a2 = make_float4(0.f, 0.f, 0.f, 0.f);
    float4 a3 = make_float4(0.f, 0.f, 0.f, 0.f);
    int j = start;
    for (; j + 3 < end; j += 4) {
        int s0 = csr_src[j];
        int s1 = csr_src[j + 1];
        int s2 = csr_src[j + 2];
        int s3 = csr_src[j + 3];
        ushort4 v0 = *(const ushort4*)&Yb[(size_t)s0 * 16 + q * 4];
        ushort4 v1 = *(const ushort4*)&Yb[(size_t)s1 * 16 + q * 4];
        ushort4 v2 = *(const ushort4*)&Yb[(size_t)s2 * 16 + q * 4];
        ushort4 v3 = *(const ushort4*)&Yb[(size_t)s3 * 16 + q * 4];
        a0.x += bf2f(v0.x); a0.y += bf2f(v0.y); a0.z += bf2f(v0.z); a0.w += bf2f(v0.w);
        a1.x += bf2f(v1.x); a1.y += bf2f(v1.y); a1.z += bf2f(v1.z); a1.w += bf2f(v1.w);
        a2.x += bf2f(v2.x); a2.y += bf2f(v2.y); a2.z += bf2f(v2.z); a2.w += bf2f(v2.w);
        a3.x += bf2f(v3.x); a3.y += bf2f(v3.y); a3.z += bf2f(v3.z); a3.w += bf2f(v3.w);
    }
    for (; j < end; ++j) {
        int s = csr_src[j];
        ushort4 v = *(const ushort4*)&Yb[(size_t)s * 16 + q * 4];
        a0.x += bf2f(v.x); a0.y += bf2f(v.y); a0.z += bf2f(v.z); a0.w += bf2f(v.w);
    }
    float4 acc;
    acc.x = (a0.x + a1.x) + (a2.x + a3.x);
    acc.y = (a0.y + a1.y) + (a2.y + a3.y);
    acc.z = (a0.z + a1.z) + (a2.z + a3.z);
    acc.w = (a0.w + a1.w) + (a2.w + a3.w);

    float4 c = *(const float4*)&c2[(size_t)node * 16 + q * 4];
    float h0 = fmaxf(c.x + acc.x * w, 0.f);
    float h1 = fmaxf(c.y + acc.y * w, 0.f);
    float h2 = fmaxf(c.z + acc.z * w, 0.f);
    float h3 = fmaxf(c.w + acc.w * w, 0.f);

    const float* Wq = &Wfc[q * 8];
    float o0 = h0 * Wq[0] + h1 * Wq[2] + h2 * Wq[4] + h3 * Wq[6];
    float o1 = h0 * Wq[1] + h1 * Wq[3] + h2 * Wq[5] + h3 * Wq[7];

    o0 += __shfl_xor(o0, 1); o0 += __shfl_xor(o0, 2);
    o1 += __shfl_xor(o1, 1); o1 += __shfl_xor(o1, 2);

    if (q == 0) ((float2*)out)[node] = make_float2(o0 + bfc[0], o1 + bfc[1]);
}

extern "C" void kernel_launch(void* const* d_in, const int* in_sizes, int n_in,
                              void* d_out, int out_size, void* d_ws, size_t ws_size,
                              hipStream_t stream)
{
    const float* x   = (const float*)d_in[0];
    const int*   ei  = (const int*)d_in[1];   // int32 (JAX default)
    const float* W1l = (const float*)d_in[2];
    const float* b1  = (const float*)d_in[3];
    const float* W1r = (const float*)d_in[4];
    const float* W2l = (const float*)d_in[5];
    const float* b2  = (const float*)d_in[6];
    const float* W2r = (const float*)d_in[7];
    const float* Wfc = (const float*)d_in[8];
    const float* bfc = (const float*)d_in[9];
    float* out = (float*)d_out;

    const int N = in_sizes[0] / 128;
    const int E = in_sizes[1] / 2;
    const int* src = ei;
    const int* dst = ei + E;

    const int NBK = (N + BK_SIZE - 1) / BK_SIZE;   // 782

    int*   bucket_cnt  = (int*)d_ws;                // NBK
    int*   bucket_base = bucket_cnt + NBK_MAX;      // NBK
    int*   gcursor     = bucket_base + NBK_MAX;     // NBK
    int*   row_start   = gcursor + NBK_MAX;         // N
    int*   row_end     = row_start + N;             // N
    int*   csr_src     = row_end + N;               // E
    unsigned short* y1b = (unsigned short*)(csr_src + E);   // N*32 bf16
    float* c1          = (float*)(y1b + (size_t)N * 32);    // N*32 f32
    unsigned short* y2b = (unsigned short*)(c1 + (size_t)N * 32); // N*16 bf16
    float* c2          = (float*)(y2b + (size_t)N * 16);    // N*16 f32
    int*   pk          = (int*)y1b;                 // E ints (dead before gemm1)

    // ---- build CSR (bucketed) ----
    hipMemsetAsync(bucket_cnt, 0, (size_t)NBK * sizeof(int), stream);
    hist_buckets<<<196, 256, 0, stream>>>(dst, bucket_cnt, E, NBK);
    scan_buckets<<<1, 1024, 0, stream>>>(bucket_cnt, bucket_base, gcursor, NBK);
    {
        int nb = (E + 256 * EPT - 1) / (256 * EPT);
        bin_scatter<<<nb, 256, 0, stream>>>(src, dst, gcursor, pk, E, NBK);
    }
    bucket_csr<<<NBK, 256, 0, stream>>>(pk, bucket_base, bucket_cnt,
                                        csr_src, row_start, row_end, N);

    // ---- layer 1 GEMM (MFMA) ----
    gemm1_mfma<<<256, TPB, 0, stream>>>(x, W1l, W1r, b1, y1b, c1, N);

    // ---- fused gather1 + relu + gemm2 ----
    gather_gemm2<<<(N * 8 + TPB - 1) / TPB, TPB, 0, stream>>>(
        row_start, row_end, csr_src, y1b, c1, W2l, W2r, b2, y2b, c2, N);

    // ---- fused gather2 + final ----
    gather_final<<<(N * 4 + TPB - 1) / TPB, TPB, 0, stream>>>(
        row_start, row_end, csr_src, y2b, c2, Wfc, bfc, out, N);
}

// Round 11
// 221.724 us; speedup vs baseline: 1.2151x; 1.0008x over previous
//
#include <hip/hip_runtime.h>

#define TPB 256
#define BK_SHIFT 7
#define BK_SIZE 128
#define NBK_MAX 800     // >= ceil(100000/128)=782
#define EPT 32          // edges per thread in bin_scatter chunks

typedef __attribute__((ext_vector_type(8))) short bf16x8;
typedef __attribute__((ext_vector_type(4))) float f32x4;

__device__ __forceinline__ unsigned short f2bf(float f) {
    unsigned u = __float_as_uint(f);
    unsigned r = (u + 0x7FFFu + ((u >> 16) & 1u)) >> 16;   // RNE
    return (unsigned short)r;
}
__device__ __forceinline__ float bf2f(unsigned short b) {
    return __uint_as_float((unsigned)b << 16);
}
__device__ __forceinline__ void acc4(float4& a, ushort4 v) {
    a.x += bf2f(v.x); a.y += bf2f(v.y); a.z += bf2f(v.z); a.w += bf2f(v.w);
}

// ---------------- bucket histogram (LDS-privatized, int4 loads) -----------
__global__ __launch_bounds__(256) void hist_buckets(
    const int* __restrict__ dst, int* __restrict__ bcnt, int E, int NBK)
{
    __shared__ int h[NBK_MAX];
    const int t = threadIdx.x;
    for (int i = t; i < NBK; i += 256) h[i] = 0;
    __syncthreads();
    const int E4 = E >> 2;
    for (int e4 = blockIdx.x * blockDim.x + t; e4 < E4; e4 += gridDim.x * blockDim.x) {
        int4 d = ((const int4*)dst)[e4];
        atomicAdd(&h[d.x >> BK_SHIFT], 1);
        atomicAdd(&h[d.y >> BK_SHIFT], 1);
        atomicAdd(&h[d.z >> BK_SHIFT], 1);
        atomicAdd(&h[d.w >> BK_SHIFT], 1);
    }
    if (blockIdx.x == 0) {
        for (int e = E4 * 4 + t; e < E; e += 256)
            atomicAdd(&h[dst[e] >> BK_SHIFT], 1);
    }
    __syncthreads();
    for (int i = t; i < NBK; i += 256)
        if (h[i]) atomicAdd(&bcnt[i], h[i]);
}

// ---------------- scan of bucket counts (one block, NBK<=1024) ------------
__global__ __launch_bounds__(1024) void scan_buckets(
    const int* __restrict__ bcnt, int* __restrict__ bbase,
    int* __restrict__ gcursor, int NBK)
{
    __shared__ int s[1024];
    const int t = threadIdx.x;
    int v = (t < NBK) ? bcnt[t] : 0;
    s[t] = v;
    __syncthreads();
    for (int off = 1; off < 1024; off <<= 1) {
        int u = (t >= off) ? s[t - off] : 0;
        __syncthreads();
        s[t] += u;
        __syncthreads();
    }
    if (t < NBK) {
        int excl = s[t] - v;
        bbase[t]   = excl;
        gcursor[t] = excl;
    }
}

// ---------------- bin scatter: pack edges into bucket-ordered pk[] --------
__global__ __launch_bounds__(256) void bin_scatter(
    const int* __restrict__ src, const int* __restrict__ dst,
    int* __restrict__ gcursor, int* __restrict__ pk, int E, int NBK)
{
    __shared__ int lcnt[NBK_MAX];
    __shared__ int lbase[NBK_MAX];
    __shared__ int lrank[NBK_MAX];
    const int t = threadIdx.x;
    const int e0 = blockIdx.x * (256 * EPT);

    for (int i = t; i < NBK; i += 256) { lcnt[i] = 0; lrank[i] = 0; }
    __syncthreads();

    #pragma unroll 4
    for (int k = 0; k < EPT; ++k) {
        int e = e0 + k * 256 + t;
        if (e < E) atomicAdd(&lcnt[dst[e] >> BK_SHIFT], 1);
    }
    __syncthreads();

    for (int i = t; i < NBK; i += 256) {
        int c = lcnt[i];
        if (c) lbase[i] = atomicAdd(&gcursor[i], c);
    }
    __syncthreads();

    #pragma unroll 4
    for (int k = 0; k < EPT; ++k) {
        int e = e0 + k * 256 + t;
        if (e < E) {
            int d = dst[e], s = src[e];
            int b = d >> BK_SHIFT;
            int r = atomicAdd(&lrank[b], 1);
            pk[lbase[b] + r] = (s << BK_SHIFT) | (d & (BK_SIZE - 1));
        }
    }
}

// ---------------- per-bucket counting sort -> exact CSR -------------------
__global__ __launch_bounds__(256) void bucket_csr(
    const int* __restrict__ pk, const int* __restrict__ bbase,
    const int* __restrict__ bcnt,
    int* __restrict__ csr_src, int* __restrict__ row_start,
    int* __restrict__ row_end, int N)
{
    __shared__ int lcnt[BK_SIZE];
    __shared__ int s[BK_SIZE];
    __shared__ int wcur[BK_SIZE];
    const int t = threadIdx.x;
    const int b = blockIdx.x;
    const int base = bbase[b];
    const int cnt  = bcnt[b];
    const int node0 = b * BK_SIZE;

    if (t < BK_SIZE) lcnt[t] = 0;
    __syncthreads();

    for (int j = t; j < cnt; j += 256)
        atomicAdd(&lcnt[pk[base + j] & (BK_SIZE - 1)], 1);
    __syncthreads();

    if (t < BK_SIZE) s[t] = lcnt[t];
    __syncthreads();
    for (int off = 1; off < BK_SIZE; off <<= 1) {
        int u = (t < BK_SIZE && t >= off) ? s[t - off] : 0;
        __syncthreads();
        if (t < BK_SIZE) s[t] += u;
        __syncthreads();
    }
    if (t < BK_SIZE) {
        int excl = s[t] - lcnt[t];
        wcur[t] = excl;
        int node = node0 + t;
        if (node < N) {
            row_start[node] = base + excl;
            row_end[node]   = base + s[t];
        }
    }
    __syncthreads();

    for (int j = t; j < cnt; j += 256) {
        int v = pk[base + j];
        int d = v & (BK_SIZE - 1);
        int pos = atomicAdd(&wcur[d], 1);
        csr_src[base + pos] = v >> BK_SHIFT;
    }
}

// ---------------- gemm1 via MFMA:  y1(bf16)=x@W1l,  c1=x@W1r+b1 -----------
__global__ __launch_bounds__(256) void gemm1_mfma(
    const float* __restrict__ A,      // x [N][128]
    const float* __restrict__ Wl,     // [128][32]
    const float* __restrict__ Wr,     // [128][32]
    const float* __restrict__ b,      // [32]
    unsigned short* __restrict__ Yb,  // y1 bf16 [N][32]
    float* __restrict__ C,            // c1 [N][32]
    int N)
{
    const int lane = threadIdx.x & 63;
    const int m    = lane & 15;
    const int quad = lane >> 4;
    const int wave   = blockIdx.x * (blockDim.x >> 6) + (threadIdx.x >> 6);
    const int nwaves = gridDim.x * (blockDim.x >> 6);
    const int ntiles = (N + 15) >> 4;

    bf16x8 Bf[4][4];   // [kc][jt]; jt 0,1 -> Wl; jt 2,3 -> Wr
    #pragma unroll
    for (int kc = 0; kc < 4; ++kc) {
        #pragma unroll
        for (int jt = 0; jt < 4; ++jt) {
            const float* W = (jt < 2) ? Wl : Wr;
            const int col = (jt & 1) * 16 + m;
            #pragma unroll
            for (int j = 0; j < 8; ++j) {
                int k = kc * 32 + quad * 8 + j;
                Bf[kc][jt][j] = (short)f2bf(W[k * 32 + col]);
            }
        }
    }

    const float bias0 = b[m];
    const float bias1 = b[16 + m];

    for (int tile = wave; tile < ntiles; tile += nwaves) {
        const int node0 = tile * 16;
        const int gn = node0 + m;
        const bool okA = gn < N;
        const float* rowp = A + (size_t)gn * 128;

        bf16x8 Af[4];
        #pragma unroll
        for (int kc = 0; kc < 4; ++kc) {
            float4 v0 = make_float4(0.f, 0.f, 0.f, 0.f);
            float4 v1 = make_float4(0.f, 0.f, 0.f, 0.f);
            if (okA) {
                v0 = *(const float4*)&rowp[kc * 32 + quad * 8];
                v1 = *(const float4*)&rowp[kc * 32 + quad * 8 + 4];
            }
            Af[kc][0] = (short)f2bf(v0.x); Af[kc][1] = (short)f2bf(v0.y);
            Af[kc][2] = (short)f2bf(v0.z); Af[kc][3] = (short)f2bf(v0.w);
            Af[kc][4] = (short)f2bf(v1.x); Af[kc][5] = (short)f2bf(v1.y);
            Af[kc][6] = (short)f2bf(v1.z); Af[kc][7] = (short)f2bf(v1.w);
        }

        f32x4 acc[4] = {{0.f,0.f,0.f,0.f},{0.f,0.f,0.f,0.f},
                        {0.f,0.f,0.f,0.f},{0.f,0.f,0.f,0.f}};
        #pragma unroll
        for (int kc = 0; kc < 4; ++kc) {
            #pragma unroll
            for (int jt = 0; jt < 4; ++jt)
                acc[jt] = __builtin_amdgcn_mfma_f32_16x16x32_bf16(
                    Af[kc], Bf[kc][jt], acc[jt], 0, 0, 0);
        }

        const int nodeBase = node0 + quad * 4;
        #pragma unroll
        for (int reg = 0; reg < 4; ++reg) {
            const int node = nodeBase + reg;
            if (node < N) {
                Yb[(size_t)node * 32 + m]      = f2bf(acc[0][reg]);
                Yb[(size_t)node * 32 + 16 + m] = f2bf(acc[1][reg]);
                C [(size_t)node * 32 + m]      = acc[2][reg] + bias0;
                C [(size_t)node * 32 + 16 + m] = acc[3][reg] + bias1;
            }
        }
    }
}

// ------- fused gather1 + relu + gemm2 (8x-unrolled gather for MLP) --------
__global__ __launch_bounds__(256) void gather_gemm2(
    const int* __restrict__ row_start, const int* __restrict__ row_end,
    const int* __restrict__ csr_src,
    const unsigned short* __restrict__ Yb,  // y1 bf16 [N][32]
    const float* __restrict__ c1,           // [N][32]
    const float* __restrict__ W2l, const float* __restrict__ W2r,
    const float* __restrict__ b2,
    unsigned short* __restrict__ y2b, float* __restrict__ c2, int N)
{
    int gid  = blockIdx.x * blockDim.x + threadIdx.x;
    int node = gid >> 3;
    int q    = gid & 7;
    const bool active = node < N;

    float h[4] = {0.f, 0.f, 0.f, 0.f};
    if (active) {
        int start = row_start[node];
        int end   = row_end[node];
        float w   = 1.0f / fmaxf((float)(end - start), 1.0f);

        float4 a0 = make_float4(0.f, 0.f, 0.f, 0.f);
        float4 a1 = make_float4(0.f, 0.f, 0.f, 0.f);
        float4 a2 = make_float4(0.f, 0.f, 0.f, 0.f);
        float4 a3 = make_float4(0.f, 0.f, 0.f, 0.f);
        int j = start;
        for (; j + 7 < end; j += 8) {
            int s0 = csr_src[j];
            int s1 = csr_src[j + 1];
            int s2 = csr_src[j + 2];
            int s3 = csr_src[j + 3];
            int s4 = csr_src[j + 4];
            int s5 = csr_src[j + 5];
            int s6 = csr_src[j + 6];
            int s7 = csr_src[j + 7];
            ushort4 v0 = *(const ushort4*)&Yb[(size_t)s0 * 32 + q * 4];
            ushort4 v1 = *(const ushort4*)&Yb[(size_t)s1 * 32 + q * 4];
            ushort4 v2 = *(const ushort4*)&Yb[(size_t)s2 * 32 + q * 4];
            ushort4 v3 = *(const ushort4*)&Yb[(size_t)s3 * 32 + q * 4];
            ushort4 v4 = *(const ushort4*)&Yb[(size_t)s4 * 32 + q * 4];
            ushort4 v5 = *(const ushort4*)&Yb[(size_t)s5 * 32 + q * 4];
            ushort4 v6 = *(const ushort4*)&Yb[(size_t)s6 * 32 + q * 4];
            ushort4 v7 = *(const ushort4*)&Yb[(size_t)s7 * 32 + q * 4];
            acc4(a0, v0); acc4(a1, v1); acc4(a2, v2); acc4(a3, v3);
            acc4(a0, v4); acc4(a1, v5); acc4(a2, v6); acc4(a3, v7);
        }
        for (; j + 3 < end; j += 4) {
            int s0 = csr_src[j];
            int s1 = csr_src[j + 1];
            int s2 = csr_src[j + 2];
            int s3 = csr_src[j + 3];
            ushort4 v0 = *(const ushort4*)&Yb[(size_t)s0 * 32 + q * 4];
            ushort4 v1 = *(const ushort4*)&Yb[(size_t)s1 * 32 + q * 4];
            ushort4 v2 = *(const ushort4*)&Yb[(size_t)s2 * 32 + q * 4];
            ushort4 v3 = *(const ushort4*)&Yb[(size_t)s3 * 32 + q * 4];
            acc4(a0, v0); acc4(a1, v1); acc4(a2, v2); acc4(a3, v3);
        }
        for (; j < end; ++j) {
            int s = csr_src[j];
            ushort4 v = *(const ushort4*)&Yb[(size_t)s * 32 + q * 4];
            acc4(a0, v);
        }
        float4 acc;
        acc.x = (a0.x + a1.x) + (a2.x + a3.x);
        acc.y = (a0.y + a1.y) + (a2.y + a3.y);
        acc.z = (a0.z + a1.z) + (a2.z + a3.z);
        acc.w = (a0.w + a1.w) + (a2.w + a3.w);

        float4 c = *(const float4*)&c1[(size_t)node * 32 + q * 4];
        h[0] = fmaxf(c.x + acc.x * w, 0.f);
        h[1] = fmaxf(c.y + acc.y * w, 0.f);
        h[2] = fmaxf(c.z + acc.z * w, 0.f);
        h[3] = fmaxf(c.w + acc.w * w, 0.f);
    }

    const int  j0  = q * 4;
    const bool isY = (j0 < 16);
    const int  jj  = isY ? j0 : (j0 - 16);
    const float* Wb = isY ? W2l : W2r;

    float o0 = 0.f, o1 = 0.f, o2 = 0.f, o3 = 0.f;
    #pragma unroll
    for (int k = 0; k < 32; ++k) {
        float hk = __shfl(h[k & 3], k >> 2, 8);
        float4 wv = *(const float4*)&Wb[k * 16 + jj];
        o0 += hk * wv.x; o1 += hk * wv.y; o2 += hk * wv.z; o3 += hk * wv.w;
    }

    if (active) {
        if (isY) {
            ushort4 r;
            r.x = f2bf(o0); r.y = f2bf(o1); r.z = f2bf(o2); r.w = f2bf(o3);
            *(ushort4*)&y2b[(size_t)node * 16 + jj] = r;
        } else {
            float4 bb = *(const float4*)&b2[jj];
            *(float4*)&c2[(size_t)node * 16 + jj] =
                make_float4(o0 + bb.x, o1 + bb.y, o2 + bb.z, o3 + bb.w);
        }
    }
}

// ------- fused gather2 + final (8x-unrolled):  out = relu(c2+mean)@Wfc+bfc
__global__ __launch_bounds__(256) void gather_final(
    const int* __restrict__ row_start, const int* __restrict__ row_end,
    const int* __restrict__ csr_src,
    const unsigned short* __restrict__ Yb,  // y2 bf16 [N][16]
    const float* __restrict__ c2,           // [N][16]
    const float* __restrict__ Wfc,          // [16][2]
    const float* __restrict__ bfc,          // [2]
    float* __restrict__ out, int N)
{
    int gid  = blockIdx.x * blockDim.x + threadIdx.x;
    int node = gid >> 2;
    int q    = gid & 3;
    if (node >= N) return;

    int start = row_start[node];
    int end   = row_end[node];
    float w   = 1.0f / fmaxf((float)(end - start), 1.0f);

    float4 a0 = make_float4(0.f, 0.f, 0.f, 0.f);
    float4 a1 = make_float4(0.f, 0.f, 0.f, 0.f);
    float4 a2 = make_float4(0.f, 0.f, 0.f, 0.f);
    float4 a3 = make_float4(0.f, 0.f, 0.f, 0.f);
    int j = start;
    for (; j + 7 < end; j += 8) {
        int s0 = csr_src[j];
        int s1 = csr_src[j + 1];
        int s2 = csr_src[j + 2];
        int s3 = csr_src[j + 3];
        int s4 = csr_src[j + 4];
        int s5 = csr_src[j + 5];
        int s6 = csr_src[j + 6];
        int s7 = csr_src[j + 7];
        ushort4 v0 = *(const ushort4*)&Yb[(size_t)s0 * 16 + q * 4];
        ushort4 v1 = *(const ushort4*)&Yb[(size_t)s1 * 16 + q * 4];
        ushort4 v2 = *(const ushort4*)&Yb[(size_t)s2 * 16 + q * 4];
        ushort4 v3 = *(const ushort4*)&Yb[(size_t)s3 * 16 + q * 4];
        ushort4 v4 = *(const ushort4*)&Yb[(size_t)s4 * 16 + q * 4];
        ushort4 v5 = *(const ushort4*)&Yb[(size_t)s5 * 16 + q * 4];
        ushort4 v6 = *(const ushort4*)&Yb[(size_t)s6 * 16 + q * 4];
        ushort4 v7 = *(const ushort4*)&Yb[(size_t)s7 * 16 + q * 4];
        acc4(a0, v0); acc4(a1, v1); acc4(a2, v2); acc4(a3, v3);
        acc4(a0, v4); acc4(a1, v5); acc4(a2, v6); acc4(a3, v7);
    }
    for (; j + 3 < end; j += 4) {
        int s0 = csr_src[j];
        int s1 = csr_src[j + 1];
        int s2 = csr_src[j + 2];
        int s3 = csr_src[j + 3];
        ushort4 v0 = *(const ushort4*)&Yb[(size_t)s0 * 16 + q * 4];
        ushort4 v1 = *(const ushort4*)&Yb[(size_t)s1 * 16 + q * 4];
        ushort4 v2 = *(const ushort4*)&Yb[(size_t)s2 * 16 + q * 4];
        ushort4 v3 = *(const ushort4*)&Yb[(size_t)s3 * 16 + q * 4];
        acc4(a0, v0); acc4(a1, v1); acc4(a2, v2); acc4(a3, v3);
    }
    for (; j < end; ++j) {
        int s = csr_src[j];
        ushort4 v = *(const ushort4*)&Yb[(size_t)s * 16 + q * 4];
        acc4(a0, v);
    }
    float4 acc;
    acc.x = (a0.x + a1.x) + (a2.x + a3.x);
    acc.y = (a0.y + a1.y) + (a2.y + a3.y);
    acc.z = (a0.z + a1.z) + (a2.z + a3.z);
    acc.w = (a0.w + a1.w) + (a2.w + a3.w);

    float4 c = *(const float4*)&c2[(size_t)node * 16 + q * 4];
    float h0 = fmaxf(c.x + acc.x * w, 0.f);
    float h1 = fmaxf(c.y + acc.y * w, 0.f);
    float h2 = fmaxf(c.z + acc.z * w, 0.f);
    float h3 = fmaxf(c.w + acc.w * w, 0.f);

    const float* Wq = &Wfc[q * 8];
    float o0 = h0 * Wq[0] + h1 * Wq[2] + h2 * Wq[4] + h3 * Wq[6];
    float o1 = h0 * Wq[1] + h1 * Wq[3] + h2 * Wq[5] + h3 * Wq[7];

    o0 += __shfl_xor(o0, 1); o0 += __shfl_xor(o0, 2);
    o1 += __shfl_xor(o1, 1); o1 += __shfl_xor(o1, 2);

    if (q == 0) ((float2*)out)[node] = make_float2(o0 + bfc[0], o1 + bfc[1]);
}

extern "C" void kernel_launch(void* const* d_in, const int* in_sizes, int n_in,
                              void* d_out, int out_size, void* d_ws, size_t ws_size,
                              hipStream_t stream)
{
    const float* x   = (const float*)d_in[0];
    const int*   ei  = (const int*)d_in[1];   // int32 (JAX default)
    const float* W1l = (const float*)d_in[2];
    const float* b1  = (const float*)d_in[3];
    const float* W1r = (const float*)d_in[4];
    const float* W2l = (const float*)d_in[5];
    const float* b2  = (const float*)d_in[6];
    const float* W2r = (const float*)d_in[7];
    const float* Wfc = (const float*)d_in[8];
    const float* bfc = (const float*)d_in[9];
    float* out = (float*)d_out;

    const int N = in_sizes[0] / 128;
    const int E = in_sizes[1] / 2;
    const int* src = ei;
    const int* dst = ei + E;

    const int NBK = (N + BK_SIZE - 1) / BK_SIZE;   // 782

    int*   bucket_cnt  = (int*)d_ws;                // NBK
    int*   bucket_base = bucket_cnt + NBK_MAX;      // NBK
    int*   gcursor     = bucket_base + NBK_MAX;     // NBK
    int*   row_start   = gcursor + NBK_MAX;         // N
    int*   row_end     = row_start + N;             // N
    int*   csr_src     = row_end + N;               // E
    unsigned short* y1b = (unsigned short*)(csr_src + E);   // N*32 bf16
    float* c1          = (float*)(y1b + (size_t)N * 32);    // N*32 f32
    unsigned short* y2b = (unsigned short*)(c1 + (size_t)N * 32); // N*16 bf16
    float* c2          = (float*)(y2b + (size_t)N * 16);    // N*16 f32
    int*   pk          = (int*)y1b;                 // E ints (dead before gemm1)

    // ---- build CSR (bucketed) ----
    hipMemsetAsync(bucket_cnt, 0, (size_t)NBK * sizeof(int), stream);
    hist_buckets<<<196, 256, 0, stream>>>(dst, bucket_cnt, E, NBK);
    scan_buckets<<<1, 1024, 0, stream>>>(bucket_cnt, bucket_base, gcursor, NBK);
    {
        int nb = (E + 256 * EPT - 1) / (256 * EPT);
        bin_scatter<<<nb, 256, 0, stream>>>(src, dst, gcursor, pk, E, NBK);
    }
    bucket_csr<<<NBK, 256, 0, stream>>>(pk, bucket_base, bucket_cnt,
                                        csr_src, row_start, row_end, N);

    // ---- layer 1 GEMM (MFMA) ----
    gemm1_mfma<<<256, TPB, 0, stream>>>(x, W1l, W1r, b1, y1b, c1, N);

    // ---- fused gather1 + relu + gemm2 ----
    gather_gemm2<<<(N * 8 + TPB - 1) / TPB, TPB, 0, stream>>>(
        row_start, row_end, csr_src, y1b, c1, W2l, W2r, b2, y2b, c2, N);

    // ---- fused gather2 + final ----
    gather_final<<<(N * 4 + TPB - 1) / TPB, TPB, 0, stream>>>(
        row_start, row_end, csr_src, y2b, c2, Wfc, bfc, out, N);
}